// Round 1
// baseline (46.410 us; speedup 1.0000x reference)
//
#include <hip/hip_runtime.h>
#include <cmath>
#include <complex>

// ChebyUpsample: x (256, 32768) f32 -> repeat x2 -> reverse -> cheby1(8,0.05,0.5)
// 4-biquad cascade -> reverse -> y (256, 65536) f32.
// Strategy: process in reversed-time domain; chunk time axis, 256 chunks/row,
// warm-up W=192 steps (dominant pole 0.933 -> residual ~1.6e-6, threshold 0.1).

struct SosC {
  float g;       // kz gain folded into section-0 input
  float a1[4];
  float a2[4];
};

__global__ __launch_bounds__(256)
void cheby_up_kernel(const float* __restrict__ x, float* __restrict__ y, SosC c) {
  const int T_IN = 32768;
  const int row = blockIdx.x;
  const int t = threadIdx.x;           // chunk index within row, 0..255
  const float* xr = x + (size_t)row * T_IN;
  float* yr = y + (size_t)row * (size_t)(2 * T_IN);

  const float g = c.g;
  const float a10 = c.a1[0], a20 = c.a2[0];
  const float a11 = c.a1[1], a21 = c.a2[1];
  const float a12 = c.a1[2], a22 = c.a2[2];
  const float a13 = c.a1[3], a23 = c.a2[3];

  // transposed direct-form II states, 4 sections
  float z10=0.f, z20=0.f, z11=0.f, z21=0.f;
  float z12=0.f, z22=0.f, z13=0.f, z23=0.f;

  // main region covers input indices j in [je, je+127]; forward outputs [2*je, 2*je+255]
  const int je = 32640 - 128 * t;

  // one filter step; b = [1,2,1] per section (gain pre-applied to x0)
  auto step = [&](float x0) -> float {
    float y0 = x0 + z10;
    z10 = fmaf(-a10, y0, fmaf(2.f, x0, z20));
    z20 = fmaf(-a20, y0, x0);
    float y1 = y0 + z11;
    z11 = fmaf(-a11, y1, fmaf(2.f, y0, z21));
    z21 = fmaf(-a21, y1, y0);
    float y2 = y1 + z12;
    z12 = fmaf(-a12, y2, fmaf(2.f, y1, z22));
    z22 = fmaf(-a22, y2, y1);
    float y3 = y2 + z13;
    z13 = fmaf(-a13, y3, fmaf(2.f, y2, z23));
    z23 = fmaf(-a23, y3, y2);
    return y3;
  };

  // ---- warm-up: 48 iterations x 4 steps = 192 steps (t==0: zero iterations, exact) ----
  int jw = je + 127 + 96;              // je+223, odd (je is even)
  if (jw > T_IN - 1) jw = T_IN - 1;    // only t==0; loop body then never executes
  for (int j = jw; j > je + 127; j -= 2) {
    float2 xx = *reinterpret_cast<const float2*>(xr + (j - 1)); // {x[j-1], x[j]}
    float xa = g * xx.y;
    float xb = g * xx.x;
    step(xa); step(xa); step(xb); step(xb);
  }

  // ---- main: 64 iterations x 4 steps = 256 outputs ----
  // step order (reversed time n ascending) hits forward indices 2j+1, 2j, 2j-1, 2j-2
  #pragma unroll 2
  for (int j = je + 127; j > je - 1; j -= 2) {
    float2 xx = *reinterpret_cast<const float2*>(xr + (j - 1)); // {x[j-1], x[j]}
    float xa = g * xx.y;
    float xb = g * xx.x;
    float wA = step(xa);   // forward index 2j+1
    float wB = step(xa);   // 2j
    float wC = step(xb);   // 2j-1
    float wD = step(xb);   // 2j-2
    float4 o = make_float4(wD, wC, wB, wA);
    *reinterpret_cast<float4*>(yr + 2 * (j - 1)) = o;  // 2(j-1) % 4 == 0 -> 16B aligned
  }
}

// Host-side replication of _cheby1_sos(8, 0.05, 0.5) in double precision.
static SosC compute_coefs() {
  const int N = 8;
  const double rp = 0.05, Wn = 0.5;
  const double PI = 3.14159265358979323846;
  double eps = std::sqrt(std::pow(10.0, 0.1 * rp) - 1.0);
  double mu = std::asinh(1.0 / eps) / (double)N;
  std::complex<double> p[8];
  std::complex<double> prodNegP(1.0, 0.0);
  int idx = 0;
  for (int m = -N + 1; m < N; m += 2) {
    double theta = PI * (double)m / (2.0 * N);
    std::complex<double> pp = -std::sinh(std::complex<double>(mu, theta));
    p[idx++] = pp;
    prodNegP *= -pp;
  }
  double k = prodNegP.real();
  k /= std::sqrt(1.0 + eps * eps);          // even N
  const double fs = 2.0;
  double warped = 2.0 * fs * std::tan(PI * Wn / fs);
  for (int i = 0; i < 8; i++) p[i] *= warped;
  k *= std::pow(warped, (double)N);
  const double fs2 = 2.0 * fs;
  std::complex<double> prodDen(1.0, 0.0);
  for (int i = 0; i < 8; i++) prodDen *= (fs2 - p[i]);
  double kz = k * (1.0 / prodDen).real();

  SosC c;
  int s = 0;
  for (int i = 0; i < 8; i++) {
    std::complex<double> pz = (fs2 + p[i]) / (fs2 - p[i]);
    if (pz.imag() > 0.0) {                  // same selection order as numpy
      c.a1[s] = (float)(-2.0 * pz.real());
      c.a2[s] = (float)std::norm(pz);       // |pz|^2
      s++;
    }
  }
  c.g = (float)kz;
  return c;
}

extern "C" void kernel_launch(void* const* d_in, const int* in_sizes, int n_in,
                              void* d_out, int out_size, void* d_ws, size_t ws_size,
                              hipStream_t stream) {
  const float* x = (const float*)d_in[0];
  float* y = (float*)d_out;
  SosC c = compute_coefs();
  int rows = in_sizes[0] / 32768;   // 256
  cheby_up_kernel<<<rows, 256, 0, stream>>>(x, y, c);
}